// Round 14
// baseline (4634.354 us; speedup 1.0000x reference)
//
#include <hip/hip_runtime.h>
#include <math.h>

// Forbid fma contraction for every expression in this file (np-matching arithmetic).
#pragma clang fp contract(off)

#define NB 8
#define NP 8192
#define NS 2048
#define NK 32

// Decision-critical f32 ops as raw VALU instructions — cannot be contracted.
__device__ __forceinline__ float fsub(float a, float b) {
  float r; asm("v_sub_f32 %0, %1, %2" : "=v"(r) : "v"(a), "v"(b)); return r;
}
__device__ __forceinline__ float fmul(float a, float b) {
  float r; asm("v_mul_f32 %0, %1, %2" : "=v"(r) : "v"(a), "v"(b)); return r;
}
__device__ __forceinline__ float fadd(float a, float b) {
  float r; asm("v_add_f32 %0, %1, %2" : "=v"(r) : "v"(a), "v"(b)); return r;
}

// ---------------- FPS: 256 threads x 32 pts, minimal redundant work ----------------
// Per-point: 12 VALU ops (no coord tracking — winner coords re-read from L2-hot xyz).
// u64 (key<<32 | ~idx) max == (max key, lowest index) == np.argmax first-occurrence.
// Single barrier per iteration via parity-double-buffered wbest.
__global__ __launch_bounds__(256, 1) void fps_kernel(const float* __restrict__ xyz,
                                                     float* __restrict__ new_xyz) {
  __shared__ unsigned long long wbest[2][4];
  const int b = blockIdx.x;
  const int tid = threadIdx.x;
  const int lane = tid & 63, wv = tid >> 6;
  const float* xb = xyz + (size_t)b * NP * 3;
  float px[32], py[32], pz[32], dist[32];
#pragma unroll
  for (int j = 0; j < 32; j++) {
    int p = j * 256 + tid;
    px[j] = xb[p * 3 + 0]; py[j] = xb[p * 3 + 1]; pz[j] = xb[p * 3 + 2];
    dist[j] = 1e10f;
  }
  float fx = xb[0], fy = xb[1], fz = xb[2];   // farthest = index 0 at t=0
  for (int t = 0; t < NS; t++) {
    if (tid == 0) {
      float* o = new_xyz + ((size_t)b * NS + t) * 3;
      o[0] = fx; o[1] = fy; o[2] = fz;
    }
    const int par = t & 1;
    float lmax = -1.0f; int larg = 0;
#pragma unroll
    for (int j = 0; j < 32; j++) {
      float dx = fsub(px[j], fx);
      float dy = fsub(py[j], fy);
      float dz = fsub(pz[j], fz);
      float d = fadd(fadd(fmul(dx, dx), fmul(dy, dy)), fmul(dz, dz));
      float nd = fminf(dist[j], d);
      dist[j] = nd;
      // ascending j => ascending global idx: strict '>' keeps lowest idx
      bool gt = nd > lmax;
      larg = gt ? (j * 256 + tid) : larg;
      lmax = gt ? nd : lmax;
    }
    // dist >= 0 => key bits unsigned-monotone; ~idx -> lowest idx wins ties
    unsigned long long m = ((unsigned long long)__float_as_uint(lmax) << 32)
                         | (unsigned long long)(unsigned)(~(unsigned)larg);
#pragma unroll
    for (int off = 32; off > 0; off >>= 1) {
      unsigned long long o2 = __shfl_down(m, off);
      if (o2 > m) m = o2;
    }
    if (lane == 0) wbest[par][wv] = m;
    __syncthreads();                    // single barrier per iteration
    unsigned long long mm = wbest[par][0];
#pragma unroll
    for (int w = 1; w < 4; w++) { unsigned long long c = wbest[par][w]; if (c > mm) mm = c; }
    int bp = (int)(~(unsigned)(mm & 0xFFFFFFFFull));   // global winner index
    // winner coords re-read from global (same bits as the register copy; L2 broadcast)
    fx = xb[bp * 3 + 0]; fy = xb[bp * 3 + 1]; fz = xb[bp * 3 + 2];
    // parity buffer: next iteration writes wbest[1-par] — no WAR race
  }
}

// ---------------- Fused ball query + gather + MLP + maxpool (unchanged from R13) ----------------
__global__ __launch_bounds__(256, 4) void ball_mlp_kernel(
    const float* __restrict__ xyz, const float* __restrict__ points,
    const float* __restrict__ new_xyz,
    const float* __restrict__ w0, const float* __restrict__ b0, const float* __restrict__ g0,
    const float* __restrict__ bt0, const float* __restrict__ m0, const float* __restrict__ v0,
    const float* __restrict__ w1, const float* __restrict__ b1, const float* __restrict__ g1,
    const float* __restrict__ bt1, const float* __restrict__ m1, const float* __restrict__ v1,
    const float* __restrict__ w2, const float* __restrict__ b2, const float* __restrict__ g2,
    const float* __restrict__ bt2, const float* __restrict__ m2, const float* __restrict__ v2,
    float* __restrict__ out_pts) {
  __shared__ __align__(16) float smem[9552];     // 38208 B -> 4 blocks/CU (LDS)
  // ---- phase A ----
  float* sd         = smem;                      // 8192 keys
  int* hist4        = (int*)(smem + 8192);       // 4 waves x 256 buckets
  int* cnts         = (int*)(smem + 9216);       // 2
  unsigned* sprefix = (unsigned*)(smem + 9218);
  int* sbelow       = (int*)(smem + 9219);
  int* snear_s      = (int*)(smem + 9220);
  int* wsum         = (int*)(smem + 9224);       // 4
  int* selA         = (int*)(smem + 9232);       // 32
  int* tib          = (int*)(smem + 9264);       // 256
  int* qsel         = (int*)(smem + 9520);       // 32 (survives into phase B)
  // ---- phase B (overlays sd) ----
  float* x1   = smem;             // 32*64
  float* x2   = smem + 2048;      // 32*64
  float* pmax = smem + 4096;      // 8*128
  float* gin  = smem + 5120;      // 32*12

  const int cs = blockIdx.x;
  const int b = cs >> 11;
  const int tid = threadIdx.x;
  const int lane = tid & 63, wv = tid >> 6;
  int* myhist = hist4 + wv * 256;
  const float* xb = xyz + (size_t)b * NP * 3;
  const float cx = new_xyz[cs * 3 + 0], cy = new_xyz[cs * 3 + 1], cz = new_xyz[cs * 3 + 2];
  const float Sc = fadd(fadd(fmul(cx, cx), fmul(cy, cy)), fmul(cz, cz));
  for (int i = lane; i < 256; i += 64) myhist[i] = 0;
  for (int j = 0; j < 32; j++) {
    int p = j * 256 + tid;
    float x = xb[p * 3 + 0], y = xb[p * 3 + 1], z = xb[p * 3 + 2];
    float Sn    = fadd(fadd(fmul(x, x), fmul(y, y)), fmul(z, z));
    float inner = fmaf(cz, z, fmaf(cy, y, fmul(cx, x)));
    float d2    = fsub(fadd(Sc, Sn), fmul(2.0f, inner));
    float kk = __fsqrt_rn(fmaxf(d2, 0.0f));
    sd[p] = kk;
    atomicAdd(&myhist[__float_as_uint(kk) >> 24], 1);
  }
  unsigned prefix = 0; int below = 0;
  for (int round = 0; round < 4; round++) {
    const int shift = 24 - 8 * round;
    if (round > 0) {
      for (int i = lane; i < 256; i += 64) myhist[i] = 0;
      __syncthreads();
      for (int j = 0; j < 32; j++) {
        unsigned kb = __float_as_uint(sd[j * 256 + tid]);
        if ((kb >> (shift + 8)) == (prefix >> (shift + 8)))
          atomicAdd(&myhist[(kb >> shift) & 255], 1);
      }
    }
    __syncthreads();
    int h = hist4[tid] + hist4[256 + tid] + hist4[512 + tid] + hist4[768 + tid];
    int v = h;
#pragma unroll
    for (int off = 1; off < 64; off <<= 1) {
      int u = __shfl_up(v, off);
      if (lane >= off) v += u;
    }
    if (lane == 63) wsum[wv] = v;
    __syncthreads();
    int base = below;
    for (int w = 0; w < wv; w++) base += wsum[w];
    int excl = base + v - h;
    if (excl < NK && excl + h >= NK) {    // unique crossing thread
      *sprefix = prefix | ((unsigned)tid << shift);
      *sbelow = excl;
    }
    __syncthreads();
    prefix = *sprefix; below = *sbelow;
  }
  const unsigned K32 = prefix;
  if (tid < 2) cnts[tid] = 0;
  __syncthreads();
  for (int j = 0; j < 32; j++) {
    int p = j * 256 + tid;
    unsigned kb = __float_as_uint(sd[p]);
    if (kb < K32) { int q = atomicAdd(&cnts[0], 1); if (q < NK) selA[q] = p; }
    else if (kb == K32) { int q = atomicAdd(&cnts[1], 1); if (q < 256) tib[q] = p; }
  }
  __syncthreads();
  const int n1 = cnts[0] < NK ? cnts[0] : NK;
  int nt = cnts[1]; if (nt > 256) nt = 256;
  if (tid == 0) {
    int need = NK - n1;
    for (int a = 0; a < need; a++) {       // ties -> lowest indices (top_k stable)
      int bj = -1; int bidx = 0x7fffffff;
      for (int j = 0; j < nt; j++) {
        int p = tib[j];
        if (p >= 0 && p < bidx) { bidx = p; bj = j; }
      }
      if (bj >= 0) { selA[n1 + a] = bidx; tib[bj] = -1; }
      else selA[n1 + a] = selA[0];
    }
    float bk = 1e30f; int bp = 0x7fffffff;  // nearest = (min key, min idx)
    for (int j = 0; j < NK; j++) {
      int p = selA[j]; float kk = sd[p];
      if (kk < bk || (kk == bk && p < bp)) { bk = kk; bp = p; }
    }
    *snear_s = bp;
  }
  __syncthreads();
  if (tid < NK) {
    int p = selA[tid];
    qsel[tid] = (sd[p] > 0.25f) ? *snear_s : p;
  }
  __syncthreads();

  // ---- phase B ----
  for (int e = tid; e < 288; e += 256) {
    int k = e / 9, c = e % 9;
    int p = qsel[k];
    float v;
    if (c < 3) {
      float cc = (c == 0) ? cx : (c == 1 ? cy : cz);
      v = fsub(xyz[((size_t)b * NP + p) * 3 + c], cc);
    } else {
      v = points[((size_t)b * NP + p) * 6 + (c - 3)];
    }
    gin[k * 12 + c] = v;
  }
  __syncthreads();
  { // L1: 1 o x 8 k per thread; w0/bn from global (L2-hot)
    int o = tid & 63, k0 = (tid >> 6) * 8;
    float wr[9];
#pragma unroll
    for (int c = 0; c < 9; c++) wr[c] = w0[o * 9 + c];
    float bb = b0[o], bm = m0[o], bg = g0[o], bbt = bt0[o];
    float br = 1.0f / __fsqrt_rn(fadd(v0[o], 1e-5f));
#pragma unroll
    for (int j = 0; j < 8; j++) {
      int k = k0 + j;
      const float4* gq = (const float4*)&gin[k * 12];
      float4 q0 = gq[0], q1 = gq[1], q2 = gq[2];
      float acc = 0.f;
      acc = fmaf(wr[0], q0.x, acc); acc = fmaf(wr[1], q0.y, acc);
      acc = fmaf(wr[2], q0.z, acc); acc = fmaf(wr[3], q0.w, acc);
      acc = fmaf(wr[4], q1.x, acc); acc = fmaf(wr[5], q1.y, acc);
      acc = fmaf(wr[6], q1.z, acc); acc = fmaf(wr[7], q1.w, acc);
      acc = fmaf(wr[8], q2.x, acc);
      float y = fadd(acc, bb);
      y = fadd(fmul(fmul(bg, fsub(y, bm)), br), bbt);
      x1[k * 64 + o] = fmaxf(y, 0.f);
    }
  }
  __syncthreads();
  { // L2: 2 o x 4 k per thread
    int o0 = (tid & 31) * 2, k0 = (tid >> 5) * 4;
    float acc[2][4];
#pragma unroll
    for (int oo = 0; oo < 2; oo++)
#pragma unroll
      for (int kk = 0; kk < 4; kk++) acc[oo][kk] = 0.f;
#pragma unroll
    for (int c4 = 0; c4 < 16; c4++) {
      float4 xq[4];
#pragma unroll
      for (int kk = 0; kk < 4; kk++) xq[kk] = *(const float4*)&x1[(k0 + kk) * 64 + c4 * 4];
#pragma unroll
      for (int oo = 0; oo < 2; oo++) {
        float4 wq = *(const float4*)&w1[(o0 + oo) * 64 + c4 * 4];
#pragma unroll
        for (int kk = 0; kk < 4; kk++) {
          acc[oo][kk] = fmaf(wq.x, xq[kk].x, acc[oo][kk]);
          acc[oo][kk] = fmaf(wq.y, xq[kk].y, acc[oo][kk]);
          acc[oo][kk] = fmaf(wq.z, xq[kk].z, acc[oo][kk]);
          acc[oo][kk] = fmaf(wq.w, xq[kk].w, acc[oo][kk]);
        }
      }
    }
#pragma unroll
    for (int oo = 0; oo < 2; oo++) {
      int o = o0 + oo;
      float bb = b1[o], bm = m1[o], bg = g1[o], bbt = bt1[o];
      float br = 1.0f / __fsqrt_rn(fadd(v1[o], 1e-5f));
#pragma unroll
      for (int kk = 0; kk < 4; kk++) {
        float y = fadd(acc[oo][kk], bb);
        y = fadd(fmul(fmul(bg, fsub(y, bm)), br), bbt);
        x2[(k0 + kk) * 64 + o] = fmaxf(y, 0.f);
      }
    }
  }
  __syncthreads();
  { // L3: 4 ch x 4 k per thread + per-k-group max
    int ch0 = (tid & 31) * 4, k0 = (tid >> 5) * 4, kg = tid >> 5;
    float acc[4][4];
#pragma unroll
    for (int cc = 0; cc < 4; cc++)
#pragma unroll
      for (int kk = 0; kk < 4; kk++) acc[cc][kk] = 0.f;
#pragma unroll
    for (int c4 = 0; c4 < 16; c4++) {
      float4 xq[4];
#pragma unroll
      for (int kk = 0; kk < 4; kk++) xq[kk] = *(const float4*)&x2[(k0 + kk) * 64 + c4 * 4];
#pragma unroll
      for (int cc = 0; cc < 4; cc++) {
        float4 wq = *(const float4*)&w2[(ch0 + cc) * 64 + c4 * 4];
#pragma unroll
        for (int kk = 0; kk < 4; kk++) {
          acc[cc][kk] = fmaf(wq.x, xq[kk].x, acc[cc][kk]);
          acc[cc][kk] = fmaf(wq.y, xq[kk].y, acc[cc][kk]);
          acc[cc][kk] = fmaf(wq.z, xq[kk].z, acc[cc][kk]);
          acc[cc][kk] = fmaf(wq.w, xq[kk].w, acc[cc][kk]);
        }
      }
    }
#pragma unroll
    for (int cc = 0; cc < 4; cc++) {
      int ch = ch0 + cc;
      float bb = b2[ch], bm = m2[ch], bg = g2[ch], bbt = bt2[ch];
      float br = 1.0f / __fsqrt_rn(fadd(v2[ch], 1e-5f));
      float mx = -1e30f;
#pragma unroll
      for (int kk = 0; kk < 4; kk++) {
        float y = fadd(acc[cc][kk], bb);
        y = fadd(fmul(fmul(bg, fsub(y, bm)), br), bbt);
        mx = fmaxf(mx, fmaxf(y, 0.f));
      }
      pmax[kg * 128 + ch] = mx;
    }
  }
  __syncthreads();
  if (tid < 128) {
    float m = pmax[tid];
#pragma unroll
    for (int g = 1; g < 8; g++) m = fmaxf(m, pmax[g * 128 + tid]);
    out_pts[(size_t)cs * 128 + tid] = m;
  }
}

extern "C" void kernel_launch(void* const* d_in, const int* in_sizes, int n_in,
                              void* d_out, int out_size, void* d_ws, size_t ws_size,
                              hipStream_t stream) {
  (void)in_sizes; (void)n_in; (void)out_size; (void)d_ws; (void)ws_size;
  const float* xyz    = (const float*)d_in[0];
  const float* points = (const float*)d_in[1];
  const float* w0 = (const float*)d_in[2];
  const float* b0 = (const float*)d_in[3];
  const float* g0 = (const float*)d_in[4];
  const float* bt0 = (const float*)d_in[5];
  const float* m0 = (const float*)d_in[6];
  const float* v0 = (const float*)d_in[7];
  const float* w1 = (const float*)d_in[8];
  const float* b1 = (const float*)d_in[9];
  const float* g1 = (const float*)d_in[10];
  const float* bt1 = (const float*)d_in[11];
  const float* m1 = (const float*)d_in[12];
  const float* v1 = (const float*)d_in[13];
  const float* w2 = (const float*)d_in[14];
  const float* b2 = (const float*)d_in[15];
  const float* g2 = (const float*)d_in[16];
  const float* bt2 = (const float*)d_in[17];
  const float* m2 = (const float*)d_in[18];
  const float* v2 = (const float*)d_in[19];

  float* new_xyz = (float*)d_out;                         // 8*2048*3 f32
  float* out_pts = (float*)d_out + (size_t)NB * NS * 3;   // 8*2048*128 f32

  fps_kernel<<<NB, 256, 0, stream>>>(xyz, new_xyz);
  ball_mlp_kernel<<<NB * NS, 256, 0, stream>>>(xyz, points, new_xyz,
                                               w0, b0, g0, bt0, m0, v0,
                                               w1, b1, g1, bt1, m1, v1,
                                               w2, b2, g2, bt2, m2, v2,
                                               out_pts);
}

// Round 15
// 3694.883 us; speedup vs baseline: 1.2543x; 1.2543x over previous
//
#include <hip/hip_runtime.h>
#include <math.h>

// Forbid fma contraction for every expression in this file (np-matching arithmetic).
#pragma clang fp contract(off)

#define NB 8
#define NP 8192
#define NS 2048
#define NK 32

// Decision-critical f32 ops as raw VALU instructions — cannot be contracted.
__device__ __forceinline__ float fsub(float a, float b) {
  float r; asm("v_sub_f32 %0, %1, %2" : "=v"(r) : "v"(a), "v"(b)); return r;
}
__device__ __forceinline__ float fmul(float a, float b) {
  float r; asm("v_mul_f32 %0, %1, %2" : "=v"(r) : "v"(a), "v"(b)); return r;
}
__device__ __forceinline__ float fadd(float a, float b) {
  float r; asm("v_add_f32 %0, %1, %2" : "=v"(r) : "v"(a), "v"(b)); return r;
}

// ---------------- FPS: 512 threads x 16 pts in NAMED SCALARS (no arrays => no scratch) ----------------
// Exact semantics of the passing kernels: unfused f32 distances; u64 (key<<32 | ~idx)
// max == (max key, lowest index) == np.argmax first-occurrence; ascending-index scan.
#define FPS_REP(X) X(0) X(1) X(2) X(3) X(4) X(5) X(6) X(7) X(8) X(9) X(10) X(11) X(12) X(13) X(14) X(15)

__global__ __launch_bounds__(512, 2) void fps_kernel(const float* __restrict__ xyz,
                                                     float* __restrict__ new_xyz) {
  __shared__ unsigned long long wbest[2][8];
  const int b = blockIdx.x;
  const int tid = threadIdx.x;
  const int lane = tid & 63, wv = tid >> 6;
  const float* xb = xyz + (size_t)b * NP * 3;

#define FPS_DECL(i) float px##i, py##i, pz##i, dist##i = 1e10f;
  FPS_REP(FPS_DECL)
#undef FPS_DECL
#define FPS_LOAD(i) { int p = (i) * 512 + tid; \
    px##i = xb[p * 3 + 0]; py##i = xb[p * 3 + 1]; pz##i = xb[p * 3 + 2]; }
  FPS_REP(FPS_LOAD)
#undef FPS_LOAD

  float fx = xb[0], fy = xb[1], fz = xb[2];   // farthest = index 0 at t=0
  for (int t = 0; t < NS; t++) {
    if (tid == 0) {
      float* o = new_xyz + ((size_t)b * NS + t) * 3;
      o[0] = fx; o[1] = fy; o[2] = fz;
    }
    const int par = t & 1;
    float lmax = -1.0f; int larg = 0;
    // ascending i => ascending global idx: strict '>' keeps lowest idx
#define FPS_UPD(i) { \
      float dx = fsub(px##i, fx); \
      float dy = fsub(py##i, fy); \
      float dz = fsub(pz##i, fz); \
      float d = fadd(fadd(fmul(dx, dx), fmul(dy, dy)), fmul(dz, dz)); \
      float nd = fminf(dist##i, d); \
      dist##i = nd; \
      bool gt = nd > lmax; \
      larg = gt ? ((i) * 512 + tid) : larg; \
      lmax = gt ? nd : lmax; }
    FPS_REP(FPS_UPD)
#undef FPS_UPD
    // dist >= 0 => key bits unsigned-monotone; ~idx -> lowest idx wins ties
    unsigned long long m = ((unsigned long long)__float_as_uint(lmax) << 32)
                         | (unsigned long long)(unsigned)(~(unsigned)larg);
#pragma unroll
    for (int off = 32; off > 0; off >>= 1) {
      unsigned long long o2 = __shfl_down(m, off);
      if (o2 > m) m = o2;
    }
    if (lane == 0) wbest[par][wv] = m;
    __syncthreads();                    // single barrier per iteration
    unsigned long long mm = wbest[par][0];
#pragma unroll
    for (int w = 1; w < 8; w++) { unsigned long long c = wbest[par][w]; if (c > mm) mm = c; }
    int bp = (int)(~(unsigned)(mm & 0xFFFFFFFFull));   // global winner index
    // winner coords re-read from global (identical bits; L2-hot broadcast)
    fx = xb[bp * 3 + 0]; fy = xb[bp * 3 + 1]; fz = xb[bp * 3 + 2];
    // parity double-buffer: next iteration writes wbest[1-par] — no WAR race
  }
}

// ---------------- Ball query (phase A of the passing kernel, unchanged semantics) ----------------
// Writes qsel[cs*32..] to global workspace for the MLP kernel.
__global__ __launch_bounds__(256, 4) void ball_kernel(
    const float* __restrict__ xyz, const float* __restrict__ new_xyz,
    int* __restrict__ qsel_ws) {
  __shared__ __align__(16) float smem[9552];
  float* sd         = smem;                      // 8192 keys
  int* hist4        = (int*)(smem + 8192);       // 4 waves x 256 buckets
  int* cnts         = (int*)(smem + 9216);       // 2
  unsigned* sprefix = (unsigned*)(smem + 9218);
  int* sbelow       = (int*)(smem + 9219);
  int* snear_s      = (int*)(smem + 9220);
  int* wsum         = (int*)(smem + 9224);       // 4
  int* selA         = (int*)(smem + 9232);       // 32
  int* tib          = (int*)(smem + 9264);       // 256

  const int cs = blockIdx.x;
  const int b = cs >> 11;
  const int tid = threadIdx.x;
  const int lane = tid & 63, wv = tid >> 6;
  int* myhist = hist4 + wv * 256;
  const float* xb = xyz + (size_t)b * NP * 3;
  const float cx = new_xyz[cs * 3 + 0], cy = new_xyz[cs * 3 + 1], cz = new_xyz[cs * 3 + 2];
  const float Sc = fadd(fadd(fmul(cx, cx), fmul(cy, cy)), fmul(cz, cz));
  for (int i = lane; i < 256; i += 64) myhist[i] = 0;
  for (int j = 0; j < 32; j++) {
    int p = j * 256 + tid;
    float x = xb[p * 3 + 0], y = xb[p * 3 + 1], z = xb[p * 3 + 2];
    float Sn    = fadd(fadd(fmul(x, x), fmul(y, y)), fmul(z, z));
    float inner = fmaf(cz, z, fmaf(cy, y, fmul(cx, x)));
    float d2    = fsub(fadd(Sc, Sn), fmul(2.0f, inner));
    float kk = __fsqrt_rn(fmaxf(d2, 0.0f));
    sd[p] = kk;
    atomicAdd(&myhist[__float_as_uint(kk) >> 24], 1);
  }
  unsigned prefix = 0; int below = 0;
  for (int round = 0; round < 4; round++) {
    const int shift = 24 - 8 * round;
    if (round > 0) {
      for (int i = lane; i < 256; i += 64) myhist[i] = 0;
      __syncthreads();
      for (int j = 0; j < 32; j++) {
        unsigned kb = __float_as_uint(sd[j * 256 + tid]);
        if ((kb >> (shift + 8)) == (prefix >> (shift + 8)))
          atomicAdd(&myhist[(kb >> shift) & 255], 1);
      }
    }
    __syncthreads();
    int h = hist4[tid] + hist4[256 + tid] + hist4[512 + tid] + hist4[768 + tid];
    int v = h;
#pragma unroll
    for (int off = 1; off < 64; off <<= 1) {
      int u = __shfl_up(v, off);
      if (lane >= off) v += u;
    }
    if (lane == 63) wsum[wv] = v;
    __syncthreads();
    int base = below;
    for (int w = 0; w < wv; w++) base += wsum[w];
    int excl = base + v - h;
    if (excl < NK && excl + h >= NK) {    // unique crossing thread
      *sprefix = prefix | ((unsigned)tid << shift);
      *sbelow = excl;
    }
    __syncthreads();
    prefix = *sprefix; below = *sbelow;
  }
  const unsigned K32 = prefix;
  if (tid < 2) cnts[tid] = 0;
  __syncthreads();
  for (int j = 0; j < 32; j++) {
    int p = j * 256 + tid;
    unsigned kb = __float_as_uint(sd[p]);
    if (kb < K32) { int q = atomicAdd(&cnts[0], 1); if (q < NK) selA[q] = p; }
    else if (kb == K32) { int q = atomicAdd(&cnts[1], 1); if (q < 256) tib[q] = p; }
  }
  __syncthreads();
  const int n1 = cnts[0] < NK ? cnts[0] : NK;
  int nt = cnts[1]; if (nt > 256) nt = 256;
  if (tid == 0) {
    int need = NK - n1;
    for (int a = 0; a < need; a++) {       // ties -> lowest indices (top_k stable)
      int bj = -1; int bidx = 0x7fffffff;
      for (int j = 0; j < nt; j++) {
        int p = tib[j];
        if (p >= 0 && p < bidx) { bidx = p; bj = j; }
      }
      if (bj >= 0) { selA[n1 + a] = bidx; tib[bj] = -1; }
      else selA[n1 + a] = selA[0];
    }
    float bk = 1e30f; int bp = 0x7fffffff;  // nearest = (min key, min idx)
    for (int j = 0; j < NK; j++) {
      int p = selA[j]; float kk = sd[p];
      if (kk < bk || (kk == bk && p < bp)) { bk = kk; bp = p; }
    }
    *snear_s = bp;
  }
  __syncthreads();
  if (tid < NK) {
    int p = selA[tid];
    qsel_ws[(size_t)cs * NK + tid] = (sd[p] > 0.25f) ? *snear_s : p;
  }
}

// ---------------- MLP + maxpool: small LDS -> high occupancy, few barriers ----------------
__global__ __launch_bounds__(256, 4) void mlp_kernel(
    const float* __restrict__ xyz, const float* __restrict__ points,
    const float* __restrict__ new_xyz, const int* __restrict__ qsel_ws,
    const float* __restrict__ w0, const float* __restrict__ b0, const float* __restrict__ g0,
    const float* __restrict__ bt0, const float* __restrict__ m0, const float* __restrict__ v0,
    const float* __restrict__ w1, const float* __restrict__ b1, const float* __restrict__ g1,
    const float* __restrict__ bt1, const float* __restrict__ m1, const float* __restrict__ v1,
    const float* __restrict__ w2, const float* __restrict__ b2, const float* __restrict__ g2,
    const float* __restrict__ bt2, const float* __restrict__ m2, const float* __restrict__ v2,
    float* __restrict__ out_pts) {
  __shared__ __align__(16) float smem[5536];   // 22144 B
  float* x1   = smem;             // 32*64
  float* x2   = smem + 2048;      // 32*64
  float* pmax = smem + 4096;      // 8*128
  float* gin  = smem + 5120;      // 32*12
  int*   qsl  = (int*)(smem + 5504);  // 32

  const int cs = blockIdx.x;
  const int b = cs >> 11;
  const int tid = threadIdx.x;
  const float cx = new_xyz[cs * 3 + 0], cy = new_xyz[cs * 3 + 1], cz = new_xyz[cs * 3 + 2];
  if (tid < NK) qsl[tid] = qsel_ws[(size_t)cs * NK + tid];
  __syncthreads();
  for (int e = tid; e < 288; e += 256) {
    int k = e / 9, c = e % 9;
    int p = qsl[k];
    float v;
    if (c < 3) {
      float cc = (c == 0) ? cx : (c == 1 ? cy : cz);
      v = fsub(xyz[((size_t)b * NP + p) * 3 + c], cc);
    } else {
      v = points[((size_t)b * NP + p) * 6 + (c - 3)];
    }
    gin[k * 12 + c] = v;
  }
  __syncthreads();
  { // L1: 1 o x 8 k per thread; w0/bn from global (L2-hot)
    int o = tid & 63, k0 = (tid >> 6) * 8;
    float wr[9];
#pragma unroll
    for (int c = 0; c < 9; c++) wr[c] = w0[o * 9 + c];
    float bb = b0[o], bm = m0[o], bg = g0[o], bbt = bt0[o];
    float br = 1.0f / __fsqrt_rn(fadd(v0[o], 1e-5f));
#pragma unroll
    for (int j = 0; j < 8; j++) {
      int k = k0 + j;
      const float4* gq = (const float4*)&gin[k * 12];
      float4 q0 = gq[0], q1 = gq[1], q2 = gq[2];
      float acc = 0.f;
      acc = fmaf(wr[0], q0.x, acc); acc = fmaf(wr[1], q0.y, acc);
      acc = fmaf(wr[2], q0.z, acc); acc = fmaf(wr[3], q0.w, acc);
      acc = fmaf(wr[4], q1.x, acc); acc = fmaf(wr[5], q1.y, acc);
      acc = fmaf(wr[6], q1.z, acc); acc = fmaf(wr[7], q1.w, acc);
      acc = fmaf(wr[8], q2.x, acc);
      float y = fadd(acc, bb);
      y = fadd(fmul(fmul(bg, fsub(y, bm)), br), bbt);
      x1[k * 64 + o] = fmaxf(y, 0.f);
    }
  }
  __syncthreads();
  { // L2: 2 o x 4 k per thread
    int o0 = (tid & 31) * 2, k0 = (tid >> 5) * 4;
    float acc[2][4];
#pragma unroll
    for (int oo = 0; oo < 2; oo++)
#pragma unroll
      for (int kk = 0; kk < 4; kk++) acc[oo][kk] = 0.f;
#pragma unroll
    for (int c4 = 0; c4 < 16; c4++) {
      float4 xq[4];
#pragma unroll
      for (int kk = 0; kk < 4; kk++) xq[kk] = *(const float4*)&x1[(k0 + kk) * 64 + c4 * 4];
#pragma unroll
      for (int oo = 0; oo < 2; oo++) {
        float4 wq = *(const float4*)&w1[(o0 + oo) * 64 + c4 * 4];
#pragma unroll
        for (int kk = 0; kk < 4; kk++) {
          acc[oo][kk] = fmaf(wq.x, xq[kk].x, acc[oo][kk]);
          acc[oo][kk] = fmaf(wq.y, xq[kk].y, acc[oo][kk]);
          acc[oo][kk] = fmaf(wq.z, xq[kk].z, acc[oo][kk]);
          acc[oo][kk] = fmaf(wq.w, xq[kk].w, acc[oo][kk]);
        }
      }
    }
#pragma unroll
    for (int oo = 0; oo < 2; oo++) {
      int o = o0 + oo;
      float bb = b1[o], bm = m1[o], bg = g1[o], bbt = bt1[o];
      float br = 1.0f / __fsqrt_rn(fadd(v1[o], 1e-5f));
#pragma unroll
      for (int kk = 0; kk < 4; kk++) {
        float y = fadd(acc[oo][kk], bb);
        y = fadd(fmul(fmul(bg, fsub(y, bm)), br), bbt);
        x2[(k0 + kk) * 64 + o] = fmaxf(y, 0.f);
      }
    }
  }
  __syncthreads();
  { // L3: 4 ch x 4 k per thread + per-k-group max
    int ch0 = (tid & 31) * 4, k0 = (tid >> 5) * 4, kg = tid >> 5;
    float acc[4][4];
#pragma unroll
    for (int cc = 0; cc < 4; cc++)
#pragma unroll
      for (int kk = 0; kk < 4; kk++) acc[cc][kk] = 0.f;
#pragma unroll
    for (int c4 = 0; c4 < 16; c4++) {
      float4 xq[4];
#pragma unroll
      for (int kk = 0; kk < 4; kk++) xq[kk] = *(const float4*)&x2[(k0 + kk) * 64 + c4 * 4];
#pragma unroll
      for (int cc = 0; cc < 4; cc++) {
        float4 wq = *(const float4*)&w2[(ch0 + cc) * 64 + c4 * 4];
#pragma unroll
        for (int kk = 0; kk < 4; kk++) {
          acc[cc][kk] = fmaf(wq.x, xq[kk].x, acc[cc][kk]);
          acc[cc][kk] = fmaf(wq.y, xq[kk].y, acc[cc][kk]);
          acc[cc][kk] = fmaf(wq.z, xq[kk].z, acc[cc][kk]);
          acc[cc][kk] = fmaf(wq.w, xq[kk].w, acc[cc][kk]);
        }
      }
    }
#pragma unroll
    for (int cc = 0; cc < 4; cc++) {
      int ch = ch0 + cc;
      float bb = b2[ch], bm = m2[ch], bg = g2[ch], bbt = bt2[ch];
      float br = 1.0f / __fsqrt_rn(fadd(v2[ch], 1e-5f));
      float mx = -1e30f;
#pragma unroll
      for (int kk = 0; kk < 4; kk++) {
        float y = fadd(acc[cc][kk], bb);
        y = fadd(fmul(fmul(bg, fsub(y, bm)), br), bbt);
        mx = fmaxf(mx, fmaxf(y, 0.f));
      }
      pmax[kg * 128 + ch] = mx;
    }
  }
  __syncthreads();
  if (tid < 128) {
    float m = pmax[tid];
#pragma unroll
    for (int g = 1; g < 8; g++) m = fmaxf(m, pmax[g * 128 + tid]);
    out_pts[(size_t)cs * 128 + tid] = m;
  }
}

extern "C" void kernel_launch(void* const* d_in, const int* in_sizes, int n_in,
                              void* d_out, int out_size, void* d_ws, size_t ws_size,
                              hipStream_t stream) {
  (void)in_sizes; (void)n_in; (void)out_size; (void)ws_size;
  const float* xyz    = (const float*)d_in[0];
  const float* points = (const float*)d_in[1];
  const float* w0 = (const float*)d_in[2];
  const float* b0 = (const float*)d_in[3];
  const float* g0 = (const float*)d_in[4];
  const float* bt0 = (const float*)d_in[5];
  const float* m0 = (const float*)d_in[6];
  const float* v0 = (const float*)d_in[7];
  const float* w1 = (const float*)d_in[8];
  const float* b1 = (const float*)d_in[9];
  const float* g1 = (const float*)d_in[10];
  const float* bt1 = (const float*)d_in[11];
  const float* m1 = (const float*)d_in[12];
  const float* v1 = (const float*)d_in[13];
  const float* w2 = (const float*)d_in[14];
  const float* b2 = (const float*)d_in[15];
  const float* g2 = (const float*)d_in[16];
  const float* bt2 = (const float*)d_in[17];
  const float* m2 = (const float*)d_in[18];
  const float* v2 = (const float*)d_in[19];

  float* new_xyz = (float*)d_out;                         // 8*2048*3 f32
  float* out_pts = (float*)d_out + (size_t)NB * NS * 3;   // 8*2048*128 f32
  int* qsel_ws = (int*)d_ws;                              // 16384*32 ints = 2 MiB

  fps_kernel<<<NB, 512, 0, stream>>>(xyz, new_xyz);
  ball_kernel<<<NB * NS, 256, 0, stream>>>(xyz, new_xyz, qsel_ws);
  mlp_kernel<<<NB * NS, 256, 0, stream>>>(xyz, points, new_xyz, qsel_ws,
                                          w0, b0, g0, bt0, m0, v0,
                                          w1, b1, g1, bt1, m1, v1,
                                          w2, b2, g2, bt2, m2, v2,
                                          out_pts);
}